// Round 7
// baseline (11487.186 us; speedup 1.0000x reference)
//
#include <hip/hip_runtime.h>
#include <math.h>

// ---------------------------------------------------------------------------
// Round 16: R8 memory-instruction mix EXACTLY (compiler atomic loads + sc1
// atomic stores + proven gbar), R14's clean single control path, plus ONE
// register-light change: the enc0 x-projection (x@eWih0^T, read-only inputs)
// is hoisted from the post-syncthreads epilogue to the TOP of the interval,
// so its 80 cached loads + 64 FMAs execute in the latency shadow of the
// serialized atomic load ladder instead of on the critical path.
//  - Session facts honored: (a) +16 live VGPRs spills (R13) -> this adds +4
//    (xs[4], statically indexed); (b) any non-R8 load/store flavor doubles
//    TCC traffic (R14: sc1 asm, R15: global_load_lds) -> zero flavor changes,
//    x/eWih0 loads were already plain cached loads in R8's epilogue;
//    (c) placement is non-deterministic -> no roster, no co-residency waits.
//  - Arithmetic order preserved exactly (same j-order dot, same single add
//    into s[g]) -> absmax bit-identical to R8.
// ---------------------------------------------------------------------------

#define NB 128
#define NT 512
#define ND 16
#define NH 512
#define NWG 256
#define NTHR 256
#define NGRP 8

typedef __attribute__((ext_vector_type(8))) short short8;
typedef __attribute__((ext_vector_type(4))) float float4v;
typedef __attribute__((ext_vector_type(4))) unsigned int uint4v;

#define SCOPE_AGT __HIP_MEMORY_SCOPE_AGENT

// ws layout (first 16KB zeroed every launch):
//  [0, 8192)        8 groups x 1KB: flags[32] (sc1 barrier words)
//  [16384, +2MB)    8 h-planes (L 0..3, parity) 256KB each, packed 4B/elem:
//                   elem(b,k) at (k>>5)*16384 + b*128 + (k&31)*4
//  [+2MB, +512KB)   H3F fp32 planes [par][b][k]
#define BAR_BYTES 16384
#define PLANE_BYTES (NB * NH * 4)
#define CHUNK_BYTES (32 * NB * 4)
#define AH_PLANE(wsB, L, par) ((wsB) + BAR_BYTES + (size_t)((L) * 2 + (par)) * PLANE_BYTES)
#define H3F_PTR(wsB, par) ((float*)((wsB) + BAR_BYTES + 8 * (size_t)PLANE_BYTES + (size_t)(par) * NB * NH * 4))

// ---- sc1 (device coherence point) accessors ----
__device__ __forceinline__ void st_u32_agt(unsigned* p, unsigned v) {
  __hip_atomic_store(p, v, __ATOMIC_RELAXED, SCOPE_AGT);
}
__device__ __forceinline__ unsigned ld_u32_agt(const unsigned* p) {
  return __hip_atomic_load(p, __ATOMIC_RELAXED, SCOPE_AGT);
}
__device__ __forceinline__ unsigned long long ld_u64_agt(const void* p) {
  return __hip_atomic_load((const unsigned long long*)p, __ATOMIC_RELAXED, SCOPE_AGT);
}

// R8-proven 2-chunk load: compiler-emitted agent-scope atomic loads.
// DO NOT replace with hand-flagged asm (R14) or global_load_lds (R15):
// both double TCC FETCH/WRITE on this chip.
__device__ __forceinline__ void loadpair(const char* pa, const char* pb,
                                         uint4v (&d)[4]) {
#pragma unroll
  for (int r = 0; r < 2; ++r) {
    const char* base = r ? pb : pa;
    unsigned long long q0 = ld_u64_agt(base);
    unsigned long long q1 = ld_u64_agt(base + 8);
    unsigned long long q2 = ld_u64_agt(base + 16);
    unsigned long long q3 = ld_u64_agt(base + 24);
    d[2 * r][0] = (unsigned)q0; d[2 * r][1] = (unsigned)(q0 >> 32);
    d[2 * r][2] = (unsigned)q1; d[2 * r][3] = (unsigned)(q1 >> 32);
    d[2 * r + 1][0] = (unsigned)q2; d[2 * r + 1][1] = (unsigned)(q2 >> 32);
    d[2 * r + 1][2] = (unsigned)q3; d[2 * r + 1][3] = (unsigned)(q3 >> 32);
  }
}

// R5/R8 sc1 flag barrier, verbatim (proven).
__device__ __forceinline__ void gbar(unsigned* flags, int hb, unsigned& epoch) {
  ++epoch;
  __syncthreads();
  if (threadIdx.x < 64) {
    if (threadIdx.x == 0) st_u32_agt(flags + hb, epoch);
    const unsigned* fp = flags + (threadIdx.x & 31);
    for (;;) {
      unsigned v = ld_u32_agt(fp);
      if (__all((int)(v - epoch) >= 0)) break;
      __builtin_amdgcn_s_sleep(1);
    }
  }
  __syncthreads();
}

// ---- bf16 split helpers (verbatim) ----
__device__ __forceinline__ unsigned short f2bf(float f) {
  union { float f; unsigned u; } v; v.f = f;
  unsigned r = v.u + 0x7fffu + ((v.u >> 16) & 1u);
  return (unsigned short)(r >> 16);
}
__device__ __forceinline__ float bf2f(unsigned short u) {
  union { float f; unsigned u; } v; v.u = ((unsigned)u) << 16; return v.f;
}
__device__ __forceinline__ void split2(float f, unsigned short& hi, unsigned short& lo) {
  hi = f2bf(f);
  lo = f2bf(f - bf2f(hi));
}
__device__ __forceinline__ void load_wfrag(const float* __restrict__ p, short8& h, short8& l) {
#pragma unroll
  for (int j = 0; j < 8; ++j) {
    unsigned short a, b2; split2(p[j], a, b2);
    h[j] = (short)a; l[j] = (short)b2;
  }
}
__device__ __forceinline__ void load_frags_single(const float* __restrict__ W, int w, int hb, int lane,
                                                  short8 (&fh)[4][4], short8 (&fl)[4][4]) {
  const int ln = lane & 15, lq = lane >> 4;
#pragma unroll
  for (int cc = 0; cc < 4; ++cc) {
    const int k = (w * 4 + cc) * 32 + lq * 8;
#pragma unroll
    for (int g = 0; g < 4; ++g)
      load_wfrag(W + (size_t)(g * NH + hb * 16 + ln) * NH + k, fh[cc][g], fl[cc][g]);
  }
}
__device__ __forceinline__ void load_frags_concat(const float* __restrict__ Wa, const float* __restrict__ Wb,
                                                  int w, int hb, int lane,
                                                  short8 (&fh)[8][4], short8 (&fl)[8][4]) {
  const int ln = lane & 15, lq = lane >> 4;
#pragma unroll
  for (int cc = 0; cc < 8; ++cc) {
    const int k = (w * 8 + cc) * 32 + lq * 8;
    const float* W = (k < 512) ? Wa : Wb;
    const int kk = (k < 512) ? k : k - 512;
#pragma unroll
    for (int g = 0; g < 4; ++g)
      load_wfrag(W + (size_t)(g * NH + hb * 16 + ln) * NH + kk, fh[cc][g], fl[cc][g]);
  }
}

// one packed chunk (2 uint4v) -> bf16x3 MFMA into acc (verbatim)
__device__ __forceinline__ void consume2(const uint4v& a, const uint4v& b,
                                         const short8 (&wh)[4], const short8 (&wl)[4],
                                         float4v (&acc)[4]) {
  unsigned x0 = a[0], x1 = a[1], x2 = a[2], x3 = a[3];
  unsigned x4 = b[0], x5 = b[1], x6 = b[2], x7 = b[3];
  union U { unsigned u[4]; short8 s; } A, L;
  A.u[0] = (x0 & 0xffffu) | (x1 << 16);
  A.u[1] = (x2 & 0xffffu) | (x3 << 16);
  A.u[2] = (x4 & 0xffffu) | (x5 << 16);
  A.u[3] = (x6 & 0xffffu) | (x7 << 16);
  L.u[0] = (x0 >> 16) | (x1 & 0xffff0000u);
  L.u[1] = (x2 >> 16) | (x3 & 0xffff0000u);
  L.u[2] = (x4 >> 16) | (x5 & 0xffff0000u);
  L.u[3] = (x6 >> 16) | (x7 & 0xffff0000u);
  const short8 ah = A.s, al = L.s;
#pragma unroll
  for (int g = 0; g < 4; ++g) {
    acc[g] = __builtin_amdgcn_mfma_f32_16x16x32_bf16(ah, wh[g], acc[g], 0, 0, 0);
    acc[g] = __builtin_amdgcn_mfma_f32_16x16x32_bf16(ah, wl[g], acc[g], 0, 0, 0);
    acc[g] = __builtin_amdgcn_mfma_f32_16x16x32_bf16(al, wh[g], acc[g], 0, 0, 0);
  }
}
__device__ __forceinline__ void write_red(float* __restrict__ red, int w, int lane, const float4v (&acc)[4]) {
  const int ln = lane & 15, lq = lane >> 4;
#pragma unroll
  for (int g = 0; g < 4; ++g)
#pragma unroll
    for (int r = 0; r < 4; ++r)
      red[((w * 4 + g) * 16 + (lq * 4 + r)) * 16 + ln] = acc[g][r];
}
__device__ __forceinline__ void store_h(char* __restrict__ plane, int b, int hid, float h) {
  unsigned short hi, lo; split2(h, hi, lo);
  const size_t off = (size_t)(hid >> 5) * CHUNK_BYTES + (size_t)b * 128 + (size_t)(hid & 31) * 4;
  unsigned v = (unsigned)hi | ((unsigned)lo << 16);
  st_u32_agt((unsigned*)(plane + off), v);
}
__device__ __forceinline__ float sigf(float v) { return 1.f / (1.f + __expf(-v)); }

extern "C" __global__ __launch_bounds__(NTHR, 1)
void lstm_ae_kernel(const float* __restrict__ x,
                    const float* __restrict__ eWih0, const float* __restrict__ eWhh0, const float* __restrict__ eb0,
                    const float* __restrict__ eWih1, const float* __restrict__ eWhh1, const float* __restrict__ eb1,
                    const float* __restrict__ dWih0, const float* __restrict__ dWhh0, const float* __restrict__ db0,
                    const float* __restrict__ dWih1, const float* __restrict__ dWhh1, const float* __restrict__ db1,
                    const float* __restrict__ Wout,  const float* __restrict__ bout,
                    float* __restrict__ out, char* __restrict__ wsB) {
  __shared__ float red0[4 * 4 * 16 * 16];  // 16KB
  __shared__ float red1[4 * 4 * 16 * 16];  // 16KB

  const int tid = threadIdx.x;
  const int lane = tid & 63;
  const int w = tid >> 6;

  // ---- proven static mapping ----
  const int grp = (int)(blockIdx.x & 7u);
  const int hb  = (int)(blockIdx.x >> 3);

  unsigned* flags = (unsigned*)(wsB + (size_t)grp * 1024);
  unsigned epoch = 0;

  const int b0 = grp * 16;
  const int ln = lane & 15, lq = lane >> 4;
  const int aoff = (b0 + ln) * 128 + lq * 32;
  const int bi = tid >> 4, hi_ = tid & 15;
  const int b = b0 + bi, hid = hb * 16 + hi_;
  const float4v zacc = {0.f, 0.f, 0.f, 0.f};

  // ---- prologue ----
  store_h(AH_PLANE(wsB, 0, 1), b, hid, 0.f);
  store_h(AH_PLANE(wsB, 1, 1), b, hid, 0.f);
  float c0 = 0.f, c1 = 0.f, c2 = 0.f, c3 = 0.f;
  const float eb0v[4] = {eb0[hid], eb0[NH + hid], eb0[2 * NH + hid], eb0[3 * NH + hid]};
  const float eb1v[4] = {eb1[hid], eb1[NH + hid], eb1[2 * NH + hid], eb1[3 * NH + hid]};
  const float db1v[4] = {db1[hid], db1[NH + hid], db1[2 * NH + hid], db1[3 * NH + hid]};

  short8 w0h[4][4], w0l[4][4];
  short8 w1h[8][4], w1l[8][4];
  load_frags_single(eWhh0, w, hb, lane, w0h, w0l);
  load_frags_concat(eWih1, eWhh1, w, hb, lane, w1h, w1l);
  gbar(flags, hb, epoch);

  float h0fin = 0.f, h1fin = 0.f;

  // ============ encoder: interval i = enc0(t=i) || enc1(te=i-1) ============
  for (int i = 0; i <= NT; ++i) {
    const int pw = i & 1, pr = pw ^ 1;
    const int te = i - 1;
    const int pA = te & 1, pB = pA ^ 1;
    const char* p0 = AH_PLANE(wsB, 0, pr);
    const char* p1 = (w < 2) ? AH_PLANE(wsB, 0, pA) : AH_PLANE(wsB, 1, pB);
    const int c1i = (w < 2) ? w * 8 : (w - 2) * 8;
    float4v acc0[4] = {zacc, zacc, zacc, zacc};
    float4v acc1[4] = {zacc, zacc, zacc, zacc};
    uint4v d[4];

    // ---- HOISTED x-projection (read-only inputs; executes in the latency
    //      shadow of the atomic load ladder; +4 live VGPRs only) ----
    float xs[4] = {0.f, 0.f, 0.f, 0.f};
    if (i < NT) {
      const float* xr = x + ((size_t)b * NT + i) * ND;
      float xv[16];
#pragma unroll
      for (int j = 0; j < 16; ++j) xv[j] = xr[j];
#pragma unroll
      for (int g = 0; g < 4; ++g) {
        const float* wr = eWih0 + (size_t)(g * NH + hid) * ND;
        float v = 0.f;
#pragma unroll
        for (int j = 0; j < 16; ++j) v += xv[j] * wr[j];
        xs[g] = v;
      }
    }

    loadpair(p0 + (size_t)(w * 4 + 0) * CHUNK_BYTES + aoff,
             p0 + (size_t)(w * 4 + 1) * CHUNK_BYTES + aoff, d);
    consume2(d[0], d[1], w0h[0], w0l[0], acc0);
    consume2(d[2], d[3], w0h[1], w0l[1], acc0);
    loadpair(p0 + (size_t)(w * 4 + 2) * CHUNK_BYTES + aoff,
             p0 + (size_t)(w * 4 + 3) * CHUNK_BYTES + aoff, d);
    consume2(d[0], d[1], w0h[2], w0l[2], acc0);
    consume2(d[2], d[3], w0h[3], w0l[3], acc0);
    write_red(red0, w, lane, acc0);
#pragma unroll
    for (int pp = 0; pp < 4; ++pp) {
      loadpair(p1 + (size_t)(c1i + 2 * pp) * CHUNK_BYTES + aoff,
               p1 + (size_t)(c1i + 2 * pp + 1) * CHUNK_BYTES + aoff, d);
      consume2(d[0], d[1], w1h[2 * pp], w1l[2 * pp], acc1);
      consume2(d[2], d[3], w1h[2 * pp + 1], w1l[2 * pp + 1], acc1);
    }
    write_red(red1, w, lane, acc1);
    __syncthreads();

    if (i < NT) {  // enc0 epilogue (x-term precomputed above; same add order)
      float s[4];
#pragma unroll
      for (int g = 0; g < 4; ++g) {
        float v = eb0v[g];
#pragma unroll
        for (int ww = 0; ww < 4; ++ww) v += red0[((ww * 4 + g) * 16 + bi) * 16 + hi_];
        s[g] = v;
      }
#pragma unroll
      for (int g = 0; g < 4; ++g) s[g] += xs[g];
      float ig = sigf(s[0]), fg = sigf(s[1]), gg = tanhf(s[2]), og = sigf(s[3]);
      c0 = fg * c0 + ig * gg;
      float h = og * tanhf(c0);
      store_h(AH_PLANE(wsB, 0, pw), b, hid, h);
      if (i == NT - 1) h0fin = h;
    }
    if (i >= 1) {  // enc1 epilogue
      float s[4];
#pragma unroll
      for (int g = 0; g < 4; ++g) {
        float v = eb1v[g];
#pragma unroll
        for (int ww = 0; ww < 4; ++ww) v += red1[((ww * 4 + g) * 16 + bi) * 16 + hi_];
        s[g] = v;
      }
      float ig = sigf(s[0]), fg = sigf(s[1]), gg = tanhf(s[2]), og = sigf(s[3]);
      c1 = fg * c1 + ig * gg;
      float h = og * tanhf(c1);
      store_h(AH_PLANE(wsB, 1, pA), b, hid, h);
      if (te == NT - 1) h1fin = h;
    }
    gbar(flags, hb, epoch);
  }

  // ============ transition ============
  out[(size_t)NB * NT * ND + (size_t)b * NH + hid] = h1fin;  // encoding
  c2 = c0; c3 = c1;
  store_h(AH_PLANE(wsB, 2, 1), b, hid, h0fin);
  store_h(AH_PLANE(wsB, 3, 1), b, hid, h1fin);

  float Gbreg[4];
  load_frags_single(dWih0, w, hb, lane, w0h, w0l);
  {  // Gb = db0 + encoding @ dWih0^T ; A = h1 plane par1
    const char* ph = AH_PLANE(wsB, 1, 1);
    float4v acc[4] = {zacc, zacc, zacc, zacc};
    uint4v d[4];
    loadpair(ph + (size_t)(w * 4 + 0) * CHUNK_BYTES + aoff,
             ph + (size_t)(w * 4 + 1) * CHUNK_BYTES + aoff, d);
    consume2(d[0], d[1], w0h[0], w0l[0], acc);
    consume2(d[2], d[3], w0h[1], w0l[1], acc);
    loadpair(ph + (size_t)(w * 4 + 2) * CHUNK_BYTES + aoff,
             ph + (size_t)(w * 4 + 3) * CHUNK_BYTES + aoff, d);
    consume2(d[0], d[1], w0h[2], w0l[2], acc);
    consume2(d[2], d[3], w0h[3], w0l[3], acc);
    write_red(red0, w, lane, acc);
    __syncthreads();
#pragma unroll
    for (int g = 0; g < 4; ++g) {
      float v = db0[g * NH + hid];
#pragma unroll
      for (int ww = 0; ww < 4; ++ww) v += red0[((ww * 4 + g) * 16 + bi) * 16 + hi_];
      Gbreg[g] = v;
    }
  }
  load_frags_single(dWhh0, w, hb, lane, w0h, w0l);
  load_frags_concat(dWih1, dWhh1, w, hb, lane, w1h, w1l);
  gbar(flags, hb, epoch);

  // ==== decoder: interval i = proj(tp=i-2) || dec0(t=i) || dec1(te=i-1) ====
  const int idxA = hb * 8 + w * 2, idxB = idxA + 1;
  const int pbA = b0 + (idxA >> 4), pdA = idxA & 15;
  const int pbB = b0 + (idxB >> 4), pdB = idxB & 15;

  for (int i = 0; i <= NT + 1; ++i) {
    const int pw = i & 1, pr = pw ^ 1;
    const int te = i - 1, tp = i - 2;
    const int pA = te & 1, pB = pA ^ 1;
    const char* p0 = AH_PLANE(wsB, 2, pr);
    const char* p1 = (w < 2) ? AH_PLANE(wsB, 2, pA) : AH_PLANE(wsB, 3, pB);
    const int c1i = (w < 2) ? w * 8 : (w - 2) * 8;
    const float* H3 = H3F_PTR(wsB, tp & 1);
    float4v acc0[4] = {zacc, zacc, zacc, zacc};
    float4v acc1[4] = {zacc, zacc, zacc, zacc};
    uint4v d[4];

    loadpair(p0 + (size_t)(w * 4 + 0) * CHUNK_BYTES + aoff,
             p0 + (size_t)(w * 4 + 1) * CHUNK_BYTES + aoff, d);
    consume2(d[0], d[1], w0h[0], w0l[0], acc0);
    consume2(d[2], d[3], w0h[1], w0l[1], acc0);
    loadpair(p0 + (size_t)(w * 4 + 2) * CHUNK_BYTES + aoff,
             p0 + (size_t)(w * 4 + 3) * CHUNK_BYTES + aoff, d);
    consume2(d[0], d[1], w0h[2], w0l[2], acc0);
    consume2(d[2], d[3], w0h[3], w0l[3], acc0);
    write_red(red0, w, lane, acc0);
#pragma unroll
    for (int pp = 0; pp < 4; ++pp) {
      loadpair(p1 + (size_t)(c1i + 2 * pp) * CHUNK_BYTES + aoff,
               p1 + (size_t)(c1i + 2 * pp + 1) * CHUNK_BYTES + aoff, d);
      consume2(d[0], d[1], w1h[2 * pp], w1l[2 * pp], acc1);
      consume2(d[2], d[3], w1h[2 * pp + 1], w1l[2 * pp + 1], acc1);
    }
    write_red(red1, w, lane, acc1);
    // projection rows for tp (read-after-barrier state)
    uint4v dp[4];
    loadpair((const char*)(H3 + (size_t)pbA * NH) + (size_t)lane * 32,
             (const char*)(H3 + (size_t)pbB * NH) + (size_t)lane * 32, dp);
    __syncthreads();

    if (i >= 2) {  // projection epilogue
#pragma unroll
      for (int rep = 0; rep < 2; ++rep) {
        union PU { uint4v u; float f[4]; } u0, u1;
        u0.u = dp[2 * rep]; u1.u = dp[2 * rep + 1];
        const int pd = rep ? pdB : pdA;
        const float* wr = Wout + (size_t)pd * NH + lane * 8;
        float ssum = u0.f[0] * wr[0] + u0.f[1] * wr[1] + u0.f[2] * wr[2] + u0.f[3] * wr[3]
                   + u1.f[0] * wr[4] + u1.f[1] * wr[5] + u1.f[2] * wr[6] + u1.f[3] * wr[7];
#pragma unroll
        for (int off = 32; off >= 1; off >>= 1) ssum += __shfl_xor(ssum, off, 64);
        if (lane == 0)
          out[((size_t)(rep ? pbB : pbA) * NT + tp) * ND + pd] = ssum + bout[pd];
      }
    }
    if (i < NT) {  // dec0 epilogue
      float s[4];
#pragma unroll
      for (int g = 0; g < 4; ++g) {
        float v = Gbreg[g];
#pragma unroll
        for (int ww = 0; ww < 4; ++ww) v += red0[((ww * 4 + g) * 16 + bi) * 16 + hi_];
        s[g] = v;
      }
      float ig = sigf(s[0]), fg = sigf(s[1]), gg = tanhf(s[2]), og = sigf(s[3]);
      c2 = fg * c2 + ig * gg;
      float h = og * tanhf(c2);
      store_h(AH_PLANE(wsB, 2, pw), b, hid, h);
    }
    if (i >= 1 && i <= NT) {  // dec1 epilogue
      float s[4];
#pragma unroll
      for (int g = 0; g < 4; ++g) {
        float v = db1v[g];
#pragma unroll
        for (int ww = 0; ww < 4; ++ww) v += red1[((ww * 4 + g) * 16 + bi) * 16 + hi_];
        s[g] = v;
      }
      float ig = sigf(s[0]), fg = sigf(s[1]), gg = tanhf(s[2]), og = sigf(s[3]);
      c3 = fg * c3 + ig * gg;
      float h = og * tanhf(c3);
      store_h(AH_PLANE(wsB, 3, pA), b, hid, h);
      __hip_atomic_store(H3F_PTR(wsB, pA) + (size_t)b * NH + hid, h,
                         __ATOMIC_RELAXED, SCOPE_AGT);
    }
    if (i != NT + 1) gbar(flags, hb, epoch);
  }
}

extern "C" void kernel_launch(void* const* d_in, const int* in_sizes, int n_in,
                              void* d_out, int out_size, void* d_ws, size_t ws_size,
                              hipStream_t stream) {
  const float* xp    = (const float*)d_in[0];
  const float* eWih0 = (const float*)d_in[1];
  const float* eWhh0 = (const float*)d_in[2];
  const float* eb0   = (const float*)d_in[3];
  const float* eWih1 = (const float*)d_in[4];
  const float* eWhh1 = (const float*)d_in[5];
  const float* eb1   = (const float*)d_in[6];
  const float* dWih0 = (const float*)d_in[7];
  const float* dWhh0 = (const float*)d_in[8];
  const float* db0   = (const float*)d_in[9];
  const float* dWih1 = (const float*)d_in[10];
  const float* dWhh1 = (const float*)d_in[11];
  const float* db1   = (const float*)d_in[12];
  const float* Wout  = (const float*)d_in[13];
  const float* bout  = (const float*)d_in[14];

  hipMemsetAsync(d_ws, 0, BAR_BYTES, stream);  // barrier flags
  lstm_ae_kernel<<<NWG, NTHR, 0, stream>>>(
      xp, eWih0, eWhh0, eb0, eWih1, eWhh1, eb1,
      dWih0, dWhh0, db0, dWih1, dWhh1, db1, Wout, bout,
      (float*)d_out, (char*)d_ws);
}

// Round 8
// 9031.950 us; speedup vs baseline: 1.2718x; 1.2718x over previous
//
#include <hip/hip_runtime.h>
#include <math.h>

// ---------------------------------------------------------------------------
// Round 17: RESTORE R8 byte-for-byte (proven 8954us, best of session).
// Post-mortem ledger (7 rounds): R13 (+16 VGPR dbuf) spilled; R14 (asm sc1
// loads) and R15 (global_load_lds) doubled TCC traffic; R16 (+4 VGPR x-hoist)
// spilled; R9-R11 (co-residency protocols) hung at 1 WG/CU capacity.
// Conclusion: this source is a knife-edge register-allocation optimum;
// every measured perturbation regresses. Restoring the exact artifact.
// ---------------------------------------------------------------------------

#define NB 128
#define NT 512
#define ND 16
#define NH 512
#define NWG 256
#define NTHR 256
#define NGRP 8
#define GWG 32

typedef __attribute__((ext_vector_type(8))) short short8;
typedef __attribute__((ext_vector_type(4))) float float4v;
typedef __attribute__((ext_vector_type(4))) unsigned int uint4v;

#define SCOPE_AGT __HIP_MEMORY_SCOPE_AGENT
#define SCOPE_WG  __HIP_MEMORY_SCOPE_WORKGROUP

// ws layout (first 16KB zeroed every launch):
//  [0, 8192)        8 groups x 1KB: flags[32] (sc1 barrier words)
//  [9216, 9248)     xcnt[8] roster counters
//  [10240, 11264)   gflags[256] one-time global barrier
//  [16384, +2MB)    8 h-planes (L 0..3, parity) 256KB each, packed 4B/elem:
//                   elem(b,k) at (k>>5)*16384 + b*128 + (k&31)*4
//  [+2MB, +512KB)   H3F fp32 planes [par][b][k]
#define BAR_BYTES 16384
#define PLANE_BYTES (NB * NH * 4)
#define CHUNK_BYTES (32 * NB * 4)
#define AH_PLANE(wsB, L, par) ((wsB) + BAR_BYTES + (size_t)((L) * 2 + (par)) * PLANE_BYTES)
#define H3F_PTR(wsB, par) ((float*)((wsB) + BAR_BYTES + 8 * (size_t)PLANE_BYTES + (size_t)(par) * NB * NH * 4))

// ---- sc1 (device coherence point) accessors ----
__device__ __forceinline__ void st_u32_agt(unsigned* p, unsigned v) {
  __hip_atomic_store(p, v, __ATOMIC_RELAXED, SCOPE_AGT);
}
__device__ __forceinline__ unsigned ld_u32_agt(const unsigned* p) {
  return __hip_atomic_load(p, __ATOMIC_RELAXED, SCOPE_AGT);
}
__device__ __forceinline__ unsigned long long ld_u64_agt(const void* p) {
  return __hip_atomic_load((const unsigned long long*)p, __ATOMIC_RELAXED, SCOPE_AGT);
}

// 2-chunk load (32B/lane each). fast: one small self-contained asm block
// (sc0 = L1-bypass, XCD-L2 coherent; wait inside; 16 early-clobber VGPRs).
// slow: sc1 atomic loads (R5-proven).
__device__ __forceinline__ void loadpair(bool fast, const char* pa, const char* pb,
                                         uint4v (&d)[4]) {
  if (fast) {
    asm volatile(
        "global_load_dwordx4 %0, %4, off sc0\n\t"
        "global_load_dwordx4 %1, %4, off offset:16 sc0\n\t"
        "global_load_dwordx4 %2, %5, off sc0\n\t"
        "global_load_dwordx4 %3, %5, off offset:16 sc0\n\t"
        "s_waitcnt vmcnt(0)"
        : "=&v"(d[0]), "=&v"(d[1]), "=&v"(d[2]), "=&v"(d[3])
        : "v"(pa), "v"(pb)
        : "memory");
  } else {
#pragma unroll
    for (int r = 0; r < 2; ++r) {
      const char* base = r ? pb : pa;
      unsigned long long q0 = ld_u64_agt(base);
      unsigned long long q1 = ld_u64_agt(base + 8);
      unsigned long long q2 = ld_u64_agt(base + 16);
      unsigned long long q3 = ld_u64_agt(base + 24);
      d[2 * r][0] = (unsigned)q0; d[2 * r][1] = (unsigned)(q0 >> 32);
      d[2 * r][2] = (unsigned)q1; d[2 * r][3] = (unsigned)(q1 >> 32);
      d[2 * r + 1][0] = (unsigned)q2; d[2 * r + 1][1] = (unsigned)(q2 >> 32);
      d[2 * r + 1][2] = (unsigned)q3; d[2 * r + 1][3] = (unsigned)(q3 >> 32);
    }
  }
}

// R5 sc1 flag barrier, verbatim (proven R5/R4). Entry __syncthreads drains
// each wave's stores (vmcnt) before the leader publishes its epoch.
__device__ __forceinline__ void gbar(unsigned* flags, int hb, unsigned& epoch) {
  ++epoch;
  __syncthreads();
  if (threadIdx.x < 64) {
    if (threadIdx.x == 0) st_u32_agt(flags + hb, epoch);
    const unsigned* fp = flags + (threadIdx.x & 31);
    for (;;) {
      unsigned v = ld_u32_agt(fp);
      if (__all((int)(v - epoch) >= 0)) break;
      __builtin_amdgcn_s_sleep(1);
    }
  }
  __syncthreads();
}

// ---- bf16 split helpers (R5 verbatim) ----
__device__ __forceinline__ unsigned short f2bf(float f) {
  union { float f; unsigned u; } v; v.f = f;
  unsigned r = v.u + 0x7fffu + ((v.u >> 16) & 1u);
  return (unsigned short)(r >> 16);
}
__device__ __forceinline__ float bf2f(unsigned short u) {
  union { float f; unsigned u; } v; v.u = ((unsigned)u) << 16; return v.f;
}
__device__ __forceinline__ void split2(float f, unsigned short& hi, unsigned short& lo) {
  hi = f2bf(f);
  lo = f2bf(f - bf2f(hi));
}
__device__ __forceinline__ void load_wfrag(const float* __restrict__ p, short8& h, short8& l) {
#pragma unroll
  for (int j = 0; j < 8; ++j) {
    unsigned short a, b2; split2(p[j], a, b2);
    h[j] = (short)a; l[j] = (short)b2;
  }
}
__device__ __forceinline__ void load_frags_single(const float* __restrict__ W, int w, int hb, int lane,
                                                  short8 (&fh)[4][4], short8 (&fl)[4][4]) {
  const int ln = lane & 15, lq = lane >> 4;
#pragma unroll
  for (int cc = 0; cc < 4; ++cc) {
    const int k = (w * 4 + cc) * 32 + lq * 8;
#pragma unroll
    for (int g = 0; g < 4; ++g)
      load_wfrag(W + (size_t)(g * NH + hb * 16 + ln) * NH + k, fh[cc][g], fl[cc][g]);
  }
}
__device__ __forceinline__ void load_frags_concat(const float* __restrict__ Wa, const float* __restrict__ Wb,
                                                  int w, int hb, int lane,
                                                  short8 (&fh)[8][4], short8 (&fl)[8][4]) {
  const int ln = lane & 15, lq = lane >> 4;
#pragma unroll
  for (int cc = 0; cc < 8; ++cc) {
    const int k = (w * 8 + cc) * 32 + lq * 8;
    const float* W = (k < 512) ? Wa : Wb;
    const int kk = (k < 512) ? k : k - 512;
#pragma unroll
    for (int g = 0; g < 4; ++g)
      load_wfrag(W + (size_t)(g * NH + hb * 16 + ln) * NH + kk, fh[cc][g], fl[cc][g]);
  }
}

// one packed chunk (2 uint4v) -> bf16x3 MFMA into acc
__device__ __forceinline__ void consume2(const uint4v& a, const uint4v& b,
                                         const short8 (&wh)[4], const short8 (&wl)[4],
                                         float4v (&acc)[4]) {
  unsigned x0 = a[0], x1 = a[1], x2 = a[2], x3 = a[3];
  unsigned x4 = b[0], x5 = b[1], x6 = b[2], x7 = b[3];
  union U { unsigned u[4]; short8 s; } A, L;
  A.u[0] = (x0 & 0xffffu) | (x1 << 16);
  A.u[1] = (x2 & 0xffffu) | (x3 << 16);
  A.u[2] = (x4 & 0xffffu) | (x5 << 16);
  A.u[3] = (x6 & 0xffffu) | (x7 << 16);
  L.u[0] = (x0 >> 16) | (x1 & 0xffff0000u);
  L.u[1] = (x2 >> 16) | (x3 & 0xffff0000u);
  L.u[2] = (x4 >> 16) | (x5 & 0xffff0000u);
  L.u[3] = (x6 >> 16) | (x7 & 0xffff0000u);
  const short8 ah = A.s, al = L.s;
#pragma unroll
  for (int g = 0; g < 4; ++g) {
    acc[g] = __builtin_amdgcn_mfma_f32_16x16x32_bf16(ah, wh[g], acc[g], 0, 0, 0);
    acc[g] = __builtin_amdgcn_mfma_f32_16x16x32_bf16(ah, wl[g], acc[g], 0, 0, 0);
    acc[g] = __builtin_amdgcn_mfma_f32_16x16x32_bf16(al, wh[g], acc[g], 0, 0, 0);
  }
}
__device__ __forceinline__ void write_red(float* __restrict__ red, int w, int lane, const float4v (&acc)[4]) {
  const int ln = lane & 15, lq = lane >> 4;
#pragma unroll
  for (int g = 0; g < 4; ++g)
#pragma unroll
    for (int r = 0; r < 4; ++r)
      red[((w * 4 + g) * 16 + (lq * 4 + r)) * 16 + ln] = acc[g][r];
}
__device__ __forceinline__ void store_h(bool fast, char* __restrict__ plane, int b, int hid, float h) {
  unsigned short hi, lo; split2(h, hi, lo);
  const size_t off = (size_t)(hid >> 5) * CHUNK_BYTES + (size_t)b * 128 + (size_t)(hid & 31) * 4;
  unsigned* p = (unsigned*)(plane + off);
  unsigned v = (unsigned)hi | ((unsigned)lo << 16);
  if (fast) __hip_atomic_store(p, v, __ATOMIC_RELAXED, SCOPE_WG);   // plain -> XCD L2
  else      st_u32_agt(p, v);                                       // sc1
}
__device__ __forceinline__ void st_f32s(bool fast, float* p, float v) {
  if (fast) __hip_atomic_store(p, v, __ATOMIC_RELAXED, SCOPE_WG);
  else      __hip_atomic_store(p, v, __ATOMIC_RELAXED, SCOPE_AGT);
}
__device__ __forceinline__ float sigf(float v) { return 1.f / (1.f + __expf(-v)); }

extern "C" __global__ __launch_bounds__(NTHR, 1)
void lstm_ae_kernel(const float* __restrict__ x,
                    const float* __restrict__ eWih0, const float* __restrict__ eWhh0, const float* __restrict__ eb0,
                    const float* __restrict__ eWih1, const float* __restrict__ eWhh1, const float* __restrict__ eb1,
                    const float* __restrict__ dWih0, const float* __restrict__ dWhh0, const float* __restrict__ db0,
                    const float* __restrict__ dWih1, const float* __restrict__ dWhh1, const float* __restrict__ db1,
                    const float* __restrict__ Wout,  const float* __restrict__ bout,
                    float* __restrict__ out, char* __restrict__ wsB) {
  __shared__ float red0[4 * 4 * 16 * 16];  // 16KB
  __shared__ float red1[4 * 4 * 16 * 16];  // 16KB
  __shared__ unsigned sh_slot;

  unsigned* xcnt   = (unsigned*)(wsB + 9216);   // [8]
  unsigned* gflags = (unsigned*)(wsB + 10240);  // [256]

  const int tid = threadIdx.x;
  const int lane = tid & 63;
  const int w = tid >> 6;

  // ---- roster: group := physical XCD via roster (slot = fetch_add) ----
  const unsigned xcc = (unsigned)__builtin_amdgcn_s_getreg(63508) & 15u;  // hwreg(XCC_ID=20,0,32)
  if (tid == 0)
    sh_slot = __hip_atomic_fetch_add(xcnt + (xcc & 7u), 1u, __ATOMIC_RELAXED, SCOPE_AGT);
  __syncthreads();
  const unsigned slot = sh_slot;
  // one-time device-wide verification (all counts == 32) else global
  // fallback to the R5-proven blockIdx mapping + sc1 data path.
  if (tid == 0) st_u32_agt(gflags + blockIdx.x, 1u);
  if (tid < 64) {
    for (;;) {
      int ok = 1;
#pragma unroll
      for (int j = 0; j < 4; ++j) ok &= (ld_u32_agt(gflags + lane * 4 + j) != 0u);
      if (__all(ok)) break;
      __builtin_amdgcn_s_sleep(1);
    }
  }
  __syncthreads();
  bool good = (slot < GWG);
#pragma unroll
  for (int k = 0; k < 8; ++k) good = good && (ld_u32_agt(xcnt + k) == GWG);

  const int grp = good ? (int)(xcc & 7u) : (blockIdx.x & 7);
  const int hb  = good ? (int)slot        : (blockIdx.x >> 3);
  const bool fast = good;

  unsigned* flags = (unsigned*)(wsB + (size_t)grp * 1024);
  unsigned epoch = 0;

  const int b0 = grp * 16;
  const int ln = lane & 15, lq = lane >> 4;
  const int aoff = (b0 + ln) * 128 + lq * 32;
  const int bi = tid >> 4, hi_ = tid & 15;
  const int b = b0 + bi, hid = hb * 16 + hi_;
  const float4v zacc = {0.f, 0.f, 0.f, 0.f};

  // ---- prologue ----
  store_h(fast, AH_PLANE(wsB, 0, 1), b, hid, 0.f);
  store_h(fast, AH_PLANE(wsB, 1, 1), b, hid, 0.f);
  float c0 = 0.f, c1 = 0.f, c2 = 0.f, c3 = 0.f;
  const float eb0v[4] = {eb0[hid], eb0[NH + hid], eb0[2 * NH + hid], eb0[3 * NH + hid]};
  const float eb1v[4] = {eb1[hid], eb1[NH + hid], eb1[2 * NH + hid], eb1[3 * NH + hid]};
  const float db1v[4] = {db1[hid], db1[NH + hid], db1[2 * NH + hid], db1[3 * NH + hid]};

  short8 w0h[4][4], w0l[4][4];
  short8 w1h[8][4], w1l[8][4];
  load_frags_single(eWhh0, w, hb, lane, w0h, w0l);
  load_frags_concat(eWih1, eWhh1, w, hb, lane, w1h, w1l);
  gbar(flags, hb, epoch);

  float h0fin = 0.f, h1fin = 0.f;

  // ============ encoder: interval i = enc0(t=i) || enc1(te=i-1) ============
  for (int i = 0; i <= NT; ++i) {
    const int pw = i & 1, pr = pw ^ 1;
    const int te = i - 1;
    const int pA = te & 1, pB = pA ^ 1;
    const char* p0 = AH_PLANE(wsB, 0, pr);
    const char* p1 = (w < 2) ? AH_PLANE(wsB, 0, pA) : AH_PLANE(wsB, 1, pB);
    const int c1i = (w < 2) ? w * 8 : (w - 2) * 8;
    float4v acc0[4] = {zacc, zacc, zacc, zacc};
    float4v acc1[4] = {zacc, zacc, zacc, zacc};
    uint4v d[4];

    loadpair(fast, p0 + (size_t)(w * 4 + 0) * CHUNK_BYTES + aoff,
                   p0 + (size_t)(w * 4 + 1) * CHUNK_BYTES + aoff, d);
    consume2(d[0], d[1], w0h[0], w0l[0], acc0);
    consume2(d[2], d[3], w0h[1], w0l[1], acc0);
    loadpair(fast, p0 + (size_t)(w * 4 + 2) * CHUNK_BYTES + aoff,
                   p0 + (size_t)(w * 4 + 3) * CHUNK_BYTES + aoff, d);
    consume2(d[0], d[1], w0h[2], w0l[2], acc0);
    consume2(d[2], d[3], w0h[3], w0l[3], acc0);
    write_red(red0, w, lane, acc0);
#pragma unroll
    for (int pp = 0; pp < 4; ++pp) {
      loadpair(fast, p1 + (size_t)(c1i + 2 * pp) * CHUNK_BYTES + aoff,
                     p1 + (size_t)(c1i + 2 * pp + 1) * CHUNK_BYTES + aoff, d);
      consume2(d[0], d[1], w1h[2 * pp], w1l[2 * pp], acc1);
      consume2(d[2], d[3], w1h[2 * pp + 1], w1l[2 * pp + 1], acc1);
    }
    write_red(red1, w, lane, acc1);
    __syncthreads();

    if (i < NT) {  // enc0 epilogue (+ exact fp32 x-term)
      float s[4];
#pragma unroll
      for (int g = 0; g < 4; ++g) {
        float v = eb0v[g];
#pragma unroll
        for (int ww = 0; ww < 4; ++ww) v += red0[((ww * 4 + g) * 16 + bi) * 16 + hi_];
        s[g] = v;
      }
      const float* xr = x + ((size_t)b * NT + i) * ND;
      float xv[16];
#pragma unroll
      for (int j = 0; j < 16; ++j) xv[j] = xr[j];
#pragma unroll
      for (int g = 0; g < 4; ++g) {
        const float* wr = eWih0 + (size_t)(g * NH + hid) * ND;
        float v = 0.f;
#pragma unroll
        for (int j = 0; j < 16; ++j) v += xv[j] * wr[j];
        s[g] += v;
      }
      float ig = sigf(s[0]), fg = sigf(s[1]), gg = tanhf(s[2]), og = sigf(s[3]);
      c0 = fg * c0 + ig * gg;
      float h = og * tanhf(c0);
      store_h(fast, AH_PLANE(wsB, 0, pw), b, hid, h);
      if (i == NT - 1) h0fin = h;
    }
    if (i >= 1) {  // enc1 epilogue
      float s[4];
#pragma unroll
      for (int g = 0; g < 4; ++g) {
        float v = eb1v[g];
#pragma unroll
        for (int ww = 0; ww < 4; ++ww) v += red1[((ww * 4 + g) * 16 + bi) * 16 + hi_];
        s[g] = v;
      }
      float ig = sigf(s[0]), fg = sigf(s[1]), gg = tanhf(s[2]), og = sigf(s[3]);
      c1 = fg * c1 + ig * gg;
      float h = og * tanhf(c1);
      store_h(fast, AH_PLANE(wsB, 1, pA), b, hid, h);
      if (te == NT - 1) h1fin = h;
    }
    gbar(flags, hb, epoch);
  }

  // ============ transition ============
  out[(size_t)NB * NT * ND + (size_t)b * NH + hid] = h1fin;  // encoding
  c2 = c0; c3 = c1;
  store_h(fast, AH_PLANE(wsB, 2, 1), b, hid, h0fin);
  store_h(fast, AH_PLANE(wsB, 3, 1), b, hid, h1fin);

  float Gbreg[4];
  load_frags_single(dWih0, w, hb, lane, w0h, w0l);
  {  // Gb = db0 + encoding @ dWih0^T ; A = h1 plane par1
    const char* ph = AH_PLANE(wsB, 1, 1);
    float4v acc[4] = {zacc, zacc, zacc, zacc};
    uint4v d[4];
    loadpair(fast, ph + (size_t)(w * 4 + 0) * CHUNK_BYTES + aoff,
                   ph + (size_t)(w * 4 + 1) * CHUNK_BYTES + aoff, d);
    consume2(d[0], d[1], w0h[0], w0l[0], acc);
    consume2(d[2], d[3], w0h[1], w0l[1], acc);
    loadpair(fast, ph + (size_t)(w * 4 + 2) * CHUNK_BYTES + aoff,
                   ph + (size_t)(w * 4 + 3) * CHUNK_BYTES + aoff, d);
    consume2(d[0], d[1], w0h[2], w0l[2], acc);
    consume2(d[2], d[3], w0h[3], w0l[3], acc);
    write_red(red0, w, lane, acc);
    __syncthreads();
#pragma unroll
    for (int g = 0; g < 4; ++g) {
      float v = db0[g * NH + hid];
#pragma unroll
      for (int ww = 0; ww < 4; ++ww) v += red0[((ww * 4 + g) * 16 + bi) * 16 + hi_];
      Gbreg[g] = v;
    }
  }
  load_frags_single(dWhh0, w, hb, lane, w0h, w0l);
  load_frags_concat(dWih1, dWhh1, w, hb, lane, w1h, w1l);
  gbar(flags, hb, epoch);

  // ==== decoder: interval i = proj(tp=i-2) || dec0(t=i) || dec1(te=i-1) ====
  const int idxA = hb * 8 + w * 2, idxB = idxA + 1;
  const int pbA = b0 + (idxA >> 4), pdA = idxA & 15;
  const int pbB = b0 + (idxB >> 4), pdB = idxB & 15;

  for (int i = 0; i <= NT + 1; ++i) {
    const int pw = i & 1, pr = pw ^ 1;
    const int te = i - 1, tp = i - 2;
    const int pA = te & 1, pB = pA ^ 1;
    const char* p0 = AH_PLANE(wsB, 2, pr);
    const char* p1 = (w < 2) ? AH_PLANE(wsB, 2, pA) : AH_PLANE(wsB, 3, pB);
    const int c1i = (w < 2) ? w * 8 : (w - 2) * 8;
    const float* H3 = H3F_PTR(wsB, tp & 1);
    float4v acc0[4] = {zacc, zacc, zacc, zacc};
    float4v acc1[4] = {zacc, zacc, zacc, zacc};
    uint4v d[4];

    loadpair(fast, p0 + (size_t)(w * 4 + 0) * CHUNK_BYTES + aoff,
                   p0 + (size_t)(w * 4 + 1) * CHUNK_BYTES + aoff, d);
    consume2(d[0], d[1], w0h[0], w0l[0], acc0);
    consume2(d[2], d[3], w0h[1], w0l[1], acc0);
    loadpair(fast, p0 + (size_t)(w * 4 + 2) * CHUNK_BYTES + aoff,
                   p0 + (size_t)(w * 4 + 3) * CHUNK_BYTES + aoff, d);
    consume2(d[0], d[1], w0h[2], w0l[2], acc0);
    consume2(d[2], d[3], w0h[3], w0l[3], acc0);
    write_red(red0, w, lane, acc0);
#pragma unroll
    for (int pp = 0; pp < 4; ++pp) {
      loadpair(fast, p1 + (size_t)(c1i + 2 * pp) * CHUNK_BYTES + aoff,
                     p1 + (size_t)(c1i + 2 * pp + 1) * CHUNK_BYTES + aoff, d);
      consume2(d[0], d[1], w1h[2 * pp], w1l[2 * pp], acc1);
      consume2(d[2], d[3], w1h[2 * pp + 1], w1l[2 * pp + 1], acc1);
    }
    write_red(red1, w, lane, acc1);
    // projection rows for tp (read-after-barrier state)
    uint4v dp[4];
    loadpair(fast, (const char*)(H3 + (size_t)pbA * NH) + (size_t)lane * 32,
                   (const char*)(H3 + (size_t)pbB * NH) + (size_t)lane * 32, dp);
    __syncthreads();

    if (i >= 2) {  // projection epilogue
#pragma unroll
      for (int rep = 0; rep < 2; ++rep) {
        union PU { uint4v u; float f[4]; } u0, u1;
        u0.u = dp[2 * rep]; u1.u = dp[2 * rep + 1];
        const int pd = rep ? pdB : pdA;
        const float* wr = Wout + (size_t)pd * NH + lane * 8;
        float ssum = u0.f[0] * wr[0] + u0.f[1] * wr[1] + u0.f[2] * wr[2] + u0.f[3] * wr[3]
                   + u1.f[0] * wr[4] + u1.f[1] * wr[5] + u1.f[2] * wr[6] + u1.f[3] * wr[7];
#pragma unroll
        for (int off = 32; off >= 1; off >>= 1) ssum += __shfl_xor(ssum, off, 64);
        if (lane == 0)
          out[((size_t)(rep ? pbB : pbA) * NT + tp) * ND + pd] = ssum + bout[pd];
      }
    }
    if (i < NT) {  // dec0 epilogue
      float s[4];
#pragma unroll
      for (int g = 0; g < 4; ++g) {
        float v = Gbreg[g];
#pragma unroll
        for (int ww = 0; ww < 4; ++ww) v += red0[((ww * 4 + g) * 16 + bi) * 16 + hi_];
        s[g] = v;
      }
      float ig = sigf(s[0]), fg = sigf(s[1]), gg = tanhf(s[2]), og = sigf(s[3]);
      c2 = fg * c2 + ig * gg;
      float h = og * tanhf(c2);
      store_h(fast, AH_PLANE(wsB, 2, pw), b, hid, h);
    }
    if (i >= 1 && i <= NT) {  // dec1 epilogue
      float s[4];
#pragma unroll
      for (int g = 0; g < 4; ++g) {
        float v = db1v[g];
#pragma unroll
        for (int ww = 0; ww < 4; ++ww) v += red1[((ww * 4 + g) * 16 + bi) * 16 + hi_];
        s[g] = v;
      }
      float ig = sigf(s[0]), fg = sigf(s[1]), gg = tanhf(s[2]), og = sigf(s[3]);
      c3 = fg * c3 + ig * gg;
      float h = og * tanhf(c3);
      store_h(fast, AH_PLANE(wsB, 3, pA), b, hid, h);
      st_f32s(fast, H3F_PTR(wsB, pA) + (size_t)b * NH + hid, h);
    }
    if (i != NT + 1) gbar(flags, hb, epoch);
  }
}

extern "C" void kernel_launch(void* const* d_in, const int* in_sizes, int n_in,
                              void* d_out, int out_size, void* d_ws, size_t ws_size,
                              hipStream_t stream) {
  const float* xp    = (const float*)d_in[0];
  const float* eWih0 = (const float*)d_in[1];
  const float* eWhh0 = (const float*)d_in[2];
  const float* eb0   = (const float*)d_in[3];
  const float* eWih1 = (const float*)d_in[4];
  const float* eWhh1 = (const float*)d_in[5];
  const float* eb1   = (const float*)d_in[6];
  const float* dWih0 = (const float*)d_in[7];
  const float* dWhh0 = (const float*)d_in[8];
  const float* db0   = (const float*)d_in[9];
  const float* dWih1 = (const float*)d_in[10];
  const float* dWhh1 = (const float*)d_in[11];
  const float* db1   = (const float*)d_in[12];
  const float* Wout  = (const float*)d_in[13];
  const float* bout  = (const float*)d_in[14];

  hipMemsetAsync(d_ws, 0, BAR_BYTES, stream);  // flags + roster + gflags
  lstm_ae_kernel<<<NWG, NTHR, 0, stream>>>(
      xp, eWih0, eWhh0, eb0, eWih1, eWhh1, eb1,
      dWih0, dWhh0, db0, dWih1, dWhh1, db1, Wout, bout,
      (float*)d_out, (char*)d_ws);
}